// Round 6
// baseline (148.334 us; speedup 1.0000x reference)
//
#include <hip/hip_runtime.h>

#define N_IN 5
#define N_OUT 16
#define NB 512           // bins; NB*BN = 102400 >= 100000 nodes
#define BN 200           // nodes per bin
#define CAP 7680         // global bucket capacity (mean 6250 + 18 sigma)
#define SCAP 7040        // LDS sorted-bucket capacity (mean + 10 sigma)
#define BIN_MAGIC 21474837ull
// bin = node/200 via magic: (node * 21474837) >> 32, exact for node < 41M.
// Packed edge: (l << 17) | row  (l < 200 -> 8 bits; row < 131072 -> 17 bits).

__device__ __forceinline__ int bin_of(int c) {
    return (int)(((unsigned long long)(unsigned)c * BIN_MAGIC) >> 32);
}

// ---------------------------------------------------------------------------
// Write-combined partition: 512-thread block per 2048-edge chunk (grid 1563,
// ~6 occupancy rounds/CU -> tail amortized; ~32 KB LDS -> multi-block/CU).
// Rank atomics -> 512-scan -> LDS counting-sort -> coalesced run writes.
// cursor[] = pure counts (zeroed by memset).
// ---------------------------------------------------------------------------
__global__ __launch_bounds__(512) void partition_kernel(
        const int* __restrict__ row, const int* __restrict__ col,
        int e, int* __restrict__ eb, int* __restrict__ cursor) {
    __shared__ int sEdge[2048];             // 8 KB bin-sorted packed edges
    __shared__ unsigned short sBinS[2048];  // 4 KB bin id per sorted slot
    __shared__ int hist[NB];                // 2 KB
    __shared__ int sA[NB];
    __shared__ int sB[NB];
    __shared__ int gbase[NB];
    const int tid = threadIdx.x;
    const int e4 = e >> 2;
    const int i = blockIdx.x * 512 + tid;      // int4 index
    const bool valid = i < e4;
    int rr[4], cc[4], bb[4], pr[4];
    if (valid) {
        int4 r4 = ((const int4*)row)[i];
        int4 c4 = ((const int4*)col)[i];
        rr[0] = r4.x; rr[1] = r4.y; rr[2] = r4.z; rr[3] = r4.w;
        cc[0] = c4.x; cc[1] = c4.y; cc[2] = c4.z; cc[3] = c4.w;
    }
    hist[tid] = 0;
    __syncthreads();
    if (valid) {
#pragma unroll
        for (int j = 0; j < 4; ++j) {
            bb[j] = bin_of(cc[j]);
            pr[j] = atomicAdd(&hist[bb[j]], 1);    // in-chunk rank
        }
    }
    __syncthreads();
    sA[tid] = hist[tid];
    __syncthreads();
    int* src = sA; int* dst = sB;
#pragma unroll
    for (int off = 1; off < NB; off <<= 1) {     // 9 rounds, inclusive scan
        int v = src[tid];
        if (tid >= off) v += src[tid - off];
        dst[tid] = v;
        __syncthreads();
        int* t = src; src = dst; dst = t;
    }
    {
        int h = hist[tid];
        gbase[tid] = h ? atomicAdd(&cursor[tid], h) : 0;
        dst[tid] = src[tid] - h;    // exclusive start
    }
    __syncthreads();
    int* startA = dst;
    if (valid) {
#pragma unroll
        for (int j = 0; j < 4; ++j) {
            int slot = startA[bb[j]] + pr[j];
            sEdge[slot] = ((cc[j] - bb[j] * BN) << 17) | rr[j];
            sBinS[slot] = (unsigned short)bb[j];
        }
    }
    __syncthreads();
    const int tot = src[NB - 1];
    for (int s = tid; s < tot; s += 512) {
        int b = sBinS[s];
        int pos = gbase[b] + (s - startA[b]);
        if (pos < CAP) eb[b * CAP + pos] = sEdge[s];
    }
    if (blockIdx.x == 0) {   // scalar tail (e % 4)
        for (int k = (e4 << 2) + tid; k < e; k += 512) {
            int c = col[k];
            int b = bin_of(c);
            int o = atomicAdd(&cursor[b], 1);
            if (o < CAP) eb[b * CAP + o] = ((c - b * BN) << 17) | row[k];
        }
    }
}

// ---------------------------------------------------------------------------
// K2 = sort + quant. 512-thread block per bin (grid 512 -> 2+ blocks/CU;
// ~31 KB LDS, 8 waves). Rank atomics double as degree counts; scan; LDS
// counting-sort; write eb back SORTED (coalesced int4); emit
// datom8[node] = {d*a0..d*a3 | d*a4, d, 0, 0}.
// ---------------------------------------------------------------------------
__global__ __launch_bounds__(512) void sort_quant_kernel(
        int* __restrict__ eb, const int* __restrict__ cursor,
        const float* __restrict__ atom,
        float4* __restrict__ datom8, int n) {
    __shared__ __align__(16) int lds[SCAP + 4 + 3 * BN];
    int* sebs = lds;                 // [0, SCAP+4)
    int* hist = lds + SCAP + 4;      // BN: counts -> exclusive starts
    int* sA   = lds + SCAP + 4 + BN;
    int* sB   = lds + SCAP + 4 + 2 * BN;
    const int bin = blockIdx.x;
    const int tid = threadIdx.x;
    if (tid < BN) hist[tid] = 0;
    __syncthreads();
    const int s0 = bin * CAP;
    const int cnt = min(max(cursor[bin], 0), SCAP);
    const int cnt4 = cnt >> 2;       // <= 1760 < 4*512
    const int4* ebv = (const int4*)(eb + s0);

    int4 e0, e1, e2, e3, k0, k1, k2, k3;
    const bool v0 = tid         < cnt4;
    const bool v1 = tid + 512   < cnt4;
    const bool v2 = tid + 1024  < cnt4;
    const bool v3 = tid + 1536  < cnt4;
    if (v0) { e0 = ebv[tid];
        k0.x = atomicAdd(&hist[e0.x >> 17], 1); k0.y = atomicAdd(&hist[e0.y >> 17], 1);
        k0.z = atomicAdd(&hist[e0.z >> 17], 1); k0.w = atomicAdd(&hist[e0.w >> 17], 1); }
    if (v1) { e1 = ebv[tid + 512];
        k1.x = atomicAdd(&hist[e1.x >> 17], 1); k1.y = atomicAdd(&hist[e1.y >> 17], 1);
        k1.z = atomicAdd(&hist[e1.z >> 17], 1); k1.w = atomicAdd(&hist[e1.w >> 17], 1); }
    if (v2) { e2 = ebv[tid + 1024];
        k2.x = atomicAdd(&hist[e2.x >> 17], 1); k2.y = atomicAdd(&hist[e2.y >> 17], 1);
        k2.z = atomicAdd(&hist[e2.z >> 17], 1); k2.w = atomicAdd(&hist[e2.w >> 17], 1); }
    if (v3) { e3 = ebv[tid + 1536];
        k3.x = atomicAdd(&hist[e3.x >> 17], 1); k3.y = atomicAdd(&hist[e3.y >> 17], 1);
        k3.z = atomicAdd(&hist[e3.z >> 17], 1); k3.w = atomicAdd(&hist[e3.w >> 17], 1); }
    int tl = -1, tk = 0;
    if (tid < (cnt & 3)) {
        tl = eb[s0 + (cnt4 << 2) + tid];
        tk = atomicAdd(&hist[tl >> 17], 1);
    }
    __syncthreads();

    // mydeg IS the degree (rank atomics double as the histogram).
    const int mydeg = (tid < BN) ? hist[tid] : 0;
    if (tid < BN) sA[tid] = mydeg;
    __syncthreads();
    int* src = sA; int* dst = sB;
#pragma unroll
    for (int off = 1; off < 256; off <<= 1) {    // 8 rounds covers BN=200
        if (tid < BN) {
            int v = src[tid];
            if (tid >= off) v += src[tid - off];
            dst[tid] = v;
        }
        __syncthreads();
        int* t = src; src = dst; dst = t;
    }
    if (tid < BN) hist[tid] = src[tid] - mydeg;   // exclusive start
    __syncthreads();

    // Scatter full packed values into sorted LDS order; pad to x4.
    if (v0) {
        sebs[hist[e0.x >> 17] + k0.x] = e0.x;
        sebs[hist[e0.y >> 17] + k0.y] = e0.y;
        sebs[hist[e0.z >> 17] + k0.z] = e0.z;
        sebs[hist[e0.w >> 17] + k0.w] = e0.w;
    }
    if (v1) {
        sebs[hist[e1.x >> 17] + k1.x] = e1.x;
        sebs[hist[e1.y >> 17] + k1.y] = e1.y;
        sebs[hist[e1.z >> 17] + k1.z] = e1.z;
        sebs[hist[e1.w >> 17] + k1.w] = e1.w;
    }
    if (v2) {
        sebs[hist[e2.x >> 17] + k2.x] = e2.x;
        sebs[hist[e2.y >> 17] + k2.y] = e2.y;
        sebs[hist[e2.z >> 17] + k2.z] = e2.z;
        sebs[hist[e2.w >> 17] + k2.w] = e2.w;
    }
    if (v3) {
        sebs[hist[e3.x >> 17] + k3.x] = e3.x;
        sebs[hist[e3.y >> 17] + k3.y] = e3.y;
        sebs[hist[e3.z >> 17] + k3.z] = e3.z;
        sebs[hist[e3.w >> 17] + k3.w] = e3.w;
    }
    if (tl >= 0) sebs[hist[tl >> 17] + tk] = tl;
    if (tid < 4) sebs[cnt + tid] = 0;             // pad (within SCAP+4)
    __syncthreads();

    // Coalesced sorted write-back (int4); junk pad stays inside CAP region.
    int cntw = (cnt + 3) >> 2;
    int4* ebw = (int4*)(eb + s0);
    for (int s = tid; s < cntw; s += 512)
        ebw[s] = make_int4(sebs[4 * s], sebs[4 * s + 1],
                           sebs[4 * s + 2], sebs[4 * s + 3]);

    // datom: {d*a0..d*a3 | d*a4, d, 0, 0}.
    if (tid >= BN) return;
    const int node = bin * BN + tid;
    if (node >= n) return;
    float d = rsqrtf((float)(mydeg + 1));
    const float* ap = atom + (size_t)node * N_IN;
    datom8[2 * node]     = make_float4(d * ap[0], d * ap[1], d * ap[2], d * ap[3]);
    datom8[2 * node + 1] = make_float4(d * ap[4], d, 0.0f, 0.0f);
}

// ---------------------------------------------------------------------------
// K3 = pure gather. 512-thread block per bin (~33 KB LDS -> multi-block/CU):
// coalesced int4 stage of SORTED eb into LDS, segmented edge-parallel
// register reduce (zero per-edge atomics), epilogue straight from datom8.
// ---------------------------------------------------------------------------
__global__ __launch_bounds__(512) void gather_kernel(
        const int* __restrict__ eb, const int* __restrict__ cursor,
        const float4* __restrict__ datom8,
        const float* __restrict__ W, const float* __restrict__ bias,
        float* __restrict__ out, int n) {
    __shared__ __align__(16) int sebs[SCAP];
    __shared__ float sAcc[6 * BN];
    const int bin = blockIdx.x;
    const int tid = threadIdx.x;
    const int s0 = bin * CAP;
    const int cnt = min(max(cursor[bin], 0), SCAP);
    const int cnt4 = cnt >> 2;
    const int4* ebv = (const int4*)(eb + s0);
    for (int i = tid; i < cnt4; i += 512) ((int4*)sebs)[i] = ebv[i];
    for (int i = (cnt4 << 2) + tid; i < cnt; i += 512) sebs[i] = eb[s0 + i];
    for (int q = tid; q < 6 * BN; q += 512) sAcc[q] = 0.0f;
    __syncthreads();

    // Segmented edge-parallel reduce: ~14 sorted edges per thread.
    const int ept = (cnt + 511) >> 9;
    int beg = tid * ept; if (beg > cnt) beg = cnt;
    int end = beg + ept; if (end > cnt) end = cnt;
    float a0 = 0.f, a1 = 0.f, a2 = 0.f, a3 = 0.f, a4 = 0.f, a5 = 0.f;
    int cur = -1;
    for (int ii = beg; ii < end; ++ii) {
        int v = sebs[ii];
        int l = v >> 17;
        if (l != cur) {
            if (cur >= 0) {
                atomicAdd(&sAcc[cur * 6 + 0], a0);
                atomicAdd(&sAcc[cur * 6 + 1], a1);
                atomicAdd(&sAcc[cur * 6 + 2], a2);
                atomicAdd(&sAcc[cur * 6 + 3], a3);
                atomicAdd(&sAcc[cur * 6 + 4], a4);
                atomicAdd(&sAcc[cur * 6 + 5], a5);
            }
            cur = l;
            a0 = a1 = a2 = a3 = a4 = a5 = 0.f;
        }
        int r = v & 0x1FFFF;
        float4 qa = datom8[2 * r];
        float4 qb = datom8[2 * r + 1];
        a0 += qa.x; a1 += qa.y; a2 += qa.z;
        a3 += qa.w; a4 += qb.x; a5 += qb.y;
    }
    if (cur >= 0) {
        atomicAdd(&sAcc[cur * 6 + 0], a0);
        atomicAdd(&sAcc[cur * 6 + 1], a1);
        atomicAdd(&sAcc[cur * 6 + 2], a2);
        atomicAdd(&sAcc[cur * 6 + 3], a3);
        atomicAdd(&sAcc[cur * 6 + 4], a4);
        atomicAdd(&sAcc[cur * 6 + 5], a5);
    }
    __syncthreads();

    // Epilogue: one thread per node; d and d*atom all come from datom8.
    if (tid >= BN) return;
    const int node = bin * BN + tid;
    if (node >= n) return;
    float4 qa = datom8[2 * node];
    float4 qb = datom8[2 * node + 1];
    const float d = qb.y;
    float t5[5];
    t5[0] = d * (sAcc[tid * 6 + 0] + qa.x);   // + self loop (qa = d*atom)
    t5[1] = d * (sAcc[tid * 6 + 1] + qa.y);
    t5[2] = d * (sAcc[tid * 6 + 2] + qa.z);
    t5[3] = d * (sAcc[tid * 6 + 3] + qa.w);
    t5[4] = d * (sAcc[tid * 6 + 4] + qb.x);
    const float t1 = d * (sAcc[tid * 6 + 5] + d);
    float ov[N_OUT];
#pragma unroll
    for (int o = 0; o < N_OUT; ++o) {
        float a = bias[o] * t1;
#pragma unroll
        for (int k = 0; k < 5; ++k) a = fmaf(W[o * N_IN + k], t5[k], a);
        ov[o] = fmaxf(a, 0.0f);
    }
    float4* op = (float4*)(out + (size_t)node * N_OUT);
#pragma unroll
    for (int q = 0; q < 4; ++q)
        op[q] = make_float4(ov[4 * q], ov[4 * q + 1], ov[4 * q + 2], ov[4 * q + 3]);
}

extern "C" void kernel_launch(void* const* d_in, const int* in_sizes, int n_in,
                              void* d_out, int out_size, void* d_ws, size_t ws_size,
                              hipStream_t stream) {
    const float* atom = (const float*)d_in[0];
    const int*   eidx = (const int*)d_in[1];   // [2, E] int32: row then col
    const float* W    = (const float*)d_in[2];
    const float* b    = (const float*)d_in[3];
    float* out = (float*)d_out;

    int n = in_sizes[0] / N_IN;       // 100000
    int e = in_sizes[1] / 2;          // 3200000
    const int* row = eidx;
    const int* col = eidx + e;

    // ws: cursor[NB] | eb[NB*CAP] i32 | datom8[NB*BN * 2 float4]  (~19 MB)
    auto align256 = [](size_t v) { return (v + 255) & ~(size_t)255; };
    char* w = (char*)d_ws;
    int*    cursor = (int*)w;     w += align256(NB * 4);
    int*    eb     = (int*)w;     w += align256((size_t)NB * CAP * 4);
    float4* datom8 = (float4*)w;

    int nchunk = ((e >> 2) + 511) / 512;       // one block per 2048-edge chunk
    if (nchunk < 1) nchunk = 1;

    hipMemsetAsync(cursor, 0, NB * sizeof(int), stream);
    partition_kernel<<<nchunk, 512, 0, stream>>>(row, col, e, eb, cursor);
    sort_quant_kernel<<<NB, 512, 0, stream>>>(eb, cursor, atom, datom8, n);
    gather_kernel<<<NB, 512, 0, stream>>>(eb, cursor, datom8, W, b, out, n);
}

// Round 7
// 123.901 us; speedup vs baseline: 1.1972x; 1.1972x over previous
//
#include <hip/hip_runtime.h>

#define N_IN 5
#define N_OUT 16
#define NB 256           // bins; NB*BN = 102400 >= 100000 nodes
#define BN 400           // nodes per bin
#define CAP 14336        // bucket capacity (mean 12500, sigma~111 -> +16 sigma)
#define QSCALE 1024.0f
#define QBIAS 8192
#define BIN_MAGIC 10737419ull
// bin = node/400 via magic: (node * 10737419) >> 32, exact for node <= 102400.
// Packed edge: (l << 17) | row  (l < 400 -> 9 bits; row < 131072 -> 17 bits).
// qdatom: two u64 of 3x21-bit biased fields (field = q + 8192, q clamp ±8191).
// Unsliced per-node field sums stay < 2^21 for deg < 128 (deg ~ Poisson(32)).

__device__ __forceinline__ int bin_of(int c) {
    return (int)(((unsigned long long)(unsigned)c * BIN_MAGIC) >> 32);
}

// ---------------------------------------------------------------------------
// Partition into 256 col-bins, 8192-edge chunks (2 int4 per thread), ONE
// chunk per block (grid = nchunk): halves the fork-join phase count and
// cursor reservations per edge vs the 4096-edge version. Scattered per-edge
// stores (write-combining proven neutral in R4). cursor[] = pure counts.
// ---------------------------------------------------------------------------
__global__ __launch_bounds__(1024) void partition_kernel(
        const int* __restrict__ row, const int* __restrict__ col,
        int e, int* __restrict__ eb, int* __restrict__ cursor) {
    __shared__ int hist[NB];
    __shared__ int base[NB];
    const int tid = threadIdx.x;
    const int e4 = e >> 2;
    const int i0 = blockIdx.x * 2048 + tid;      // first int4 index
    const int i1 = i0 + 1024;                    // second int4 index
    const bool valid0 = i0 < e4;
    const bool valid1 = i1 < e4;
    const int4* rowv = (const int4*)row;
    const int4* colv = (const int4*)col;
    int rr0[4], cc0[4], bb0[4], pr0[4];
    int rr1[4], cc1[4], bb1[4], pr1[4];
    if (valid0) {
        int4 r4 = rowv[i0];
        int4 c4 = colv[i0];
        rr0[0] = r4.x; rr0[1] = r4.y; rr0[2] = r4.z; rr0[3] = r4.w;
        cc0[0] = c4.x; cc0[1] = c4.y; cc0[2] = c4.z; cc0[3] = c4.w;
    }
    if (valid1) {
        int4 r4 = rowv[i1];
        int4 c4 = colv[i1];
        rr1[0] = r4.x; rr1[1] = r4.y; rr1[2] = r4.z; rr1[3] = r4.w;
        cc1[0] = c4.x; cc1[1] = c4.y; cc1[2] = c4.z; cc1[3] = c4.w;
    }
    if (tid < NB) hist[tid] = 0;
    __syncthreads();
    if (valid0) {
#pragma unroll
        for (int j = 0; j < 4; ++j) {
            bb0[j] = bin_of(cc0[j]);
            pr0[j] = atomicAdd(&hist[bb0[j]], 1);   // rank captured
        }
    }
    if (valid1) {
#pragma unroll
        for (int j = 0; j < 4; ++j) {
            bb1[j] = bin_of(cc1[j]);
            pr1[j] = atomicAdd(&hist[bb1[j]], 1);
        }
    }
    __syncthreads();
    if (tid < NB) {
        int h = hist[tid];
        base[tid] = h ? atomicAdd(&cursor[tid], h) : 0;
    }
    __syncthreads();
    if (valid0) {
#pragma unroll
        for (int j = 0; j < 4; ++j) {
            int p = base[bb0[j]] + pr0[j];
            if (p < CAP)   // capacity guard (P ~ 0)
                eb[bb0[j] * CAP + p] = ((cc0[j] - bb0[j] * BN) << 17) | rr0[j];
        }
    }
    if (valid1) {
#pragma unroll
        for (int j = 0; j < 4; ++j) {
            int p = base[bb1[j]] + pr1[j];
            if (p < CAP)
                eb[bb1[j] * CAP + p] = ((cc1[j] - bb1[j] * BN) << 17) | rr1[j];
        }
    }
    if (blockIdx.x == 0) {   // scalar tail (e % 4)
        for (int k = (e4 << 2) + tid; k < e; k += 1024) {
            int c = col[k];
            int b = bin_of(c);
            int o = atomicAdd(&cursor[b], 1);
            if (o < CAP) eb[b * CAP + o] = ((c - b * BN) << 17) | row[k];
        }
    }
}

// ---------------------------------------------------------------------------
// Block = bin: final degree hist in one pass (1 DS atomic/edge), then
// immediately dis = rsqrt(deg+1), quantized datom + deg16. (Round-0 exact.)
// ---------------------------------------------------------------------------
__global__ __launch_bounds__(1024) void deg_quant_kernel(
        const int* __restrict__ eb, const int* __restrict__ cursor,
        const float* __restrict__ atom,
        ulonglong2* __restrict__ qdatom, unsigned short* __restrict__ deg16,
        int n) {
    __shared__ int hist[BN];
    int bin = blockIdx.x;
    if (threadIdx.x < BN) hist[threadIdx.x] = 0;
    __syncthreads();
    int s0 = bin * CAP;
    int cnt = min(max(cursor[bin], 0), CAP);
    const int4* ebv = (const int4*)(eb + s0);
    int cnt4 = cnt >> 2;
    for (int i = threadIdx.x; i < cnt4; i += 1024) {
        int4 v = ebv[i];
        atomicAdd(&hist[v.x >> 17], 1);
        atomicAdd(&hist[v.y >> 17], 1);
        atomicAdd(&hist[v.z >> 17], 1);
        atomicAdd(&hist[v.w >> 17], 1);
    }
    for (int i = (cnt4 << 2) + (int)threadIdx.x; i < cnt; i += 1024)
        atomicAdd(&hist[eb[s0 + i] >> 17], 1);
    __syncthreads();
    int l = threadIdx.x;
    if (l >= BN) return;
    int node = bin * BN + l;
    if (node >= n) return;
    int deg = hist[l];
    deg16[node] = (unsigned short)deg;
    float d = rsqrtf((float)(deg + 1));
    const float* ap = atom + (size_t)node * N_IN;
    unsigned long long f[6];
#pragma unroll
    for (int k = 0; k < 5; ++k) {
        int q = __float2int_rn(d * ap[k] * QSCALE);
        q = min(max(q, -8191), 8191);
        f[k] = (unsigned long long)(q + QBIAS);
    }
    f[5] = (unsigned long long)(__float2int_rn(d * QSCALE) + QBIAS);
    ulonglong2 v;
    v.x = f[0] | (f[1] << 21) | (f[2] << 42);
    v.y = f[3] | (f[4] << 21) | (f[5] << 42);
    qdatom[node] = v;
}

// ---------------------------------------------------------------------------
// Block = bin: accumulate (2 u64 DS atomics/edge, 4-way ILP) then fused
// epilogue: debias with deg16, self-loop, Linear W/b, ReLU, 64B/node store.
// (Round-0 exact.)
// ---------------------------------------------------------------------------
__global__ __launch_bounds__(1024) void accum_final(
        const int* __restrict__ eb, const int* __restrict__ cursor,
        const ulonglong2* __restrict__ qdatom,
        const unsigned short* __restrict__ deg16,
        const float* __restrict__ atom,
        const float* __restrict__ W, const float* __restrict__ bias,
        float* __restrict__ out, int n) {
    __shared__ unsigned long long accA[BN];   // 3.2 KB
    __shared__ unsigned long long accB[BN];   // 3.2 KB
    int bin = blockIdx.x;
    if (threadIdx.x < BN) { accA[threadIdx.x] = 0ull; accB[threadIdx.x] = 0ull; }
    __syncthreads();
    int s0 = bin * CAP;
    int cnt = min(max(cursor[bin], 0), CAP);
    const int4* ebv = (const int4*)(eb + s0);
    int cnt4 = cnt >> 2;
    for (int i = threadIdx.x; i < cnt4; i += 1024) {
        int4 v = ebv[i];
        ulonglong2 q0 = qdatom[v.x & 0x1FFFF];
        ulonglong2 q1 = qdatom[v.y & 0x1FFFF];
        ulonglong2 q2 = qdatom[v.z & 0x1FFFF];
        ulonglong2 q3 = qdatom[v.w & 0x1FFFF];
        atomicAdd(&accA[v.x >> 17], q0.x);
        atomicAdd(&accB[v.x >> 17], q0.y);
        atomicAdd(&accA[v.y >> 17], q1.x);
        atomicAdd(&accB[v.y >> 17], q1.y);
        atomicAdd(&accA[v.z >> 17], q2.x);
        atomicAdd(&accB[v.z >> 17], q2.y);
        atomicAdd(&accA[v.w >> 17], q3.x);
        atomicAdd(&accB[v.w >> 17], q3.y);
    }
    for (int i = (cnt4 << 2) + (int)threadIdx.x; i < cnt; i += 1024) {
        int v = eb[s0 + i];
        ulonglong2 q = qdatom[v & 0x1FFFF];
        atomicAdd(&accA[v >> 17], q.x);
        atomicAdd(&accB[v >> 17], q.y);
    }
    __syncthreads();
    int l = threadIdx.x;
    if (l >= BN) return;
    int node = bin * BN + l;
    if (node >= n) return;
    unsigned long long SA = accA[l], SB = accB[l];
    int deg = deg16[node];
    int db = deg * QBIAS;
    const float inv = 1.0f / QSCALE;
    float s[6];
    s[0] = (float)((int)((SA      ) & 0x1FFFFF) - db) * inv;
    s[1] = (float)((int)((SA >> 21) & 0x1FFFFF) - db) * inv;
    s[2] = (float)((int)((SA >> 42) & 0x1FFFFF) - db) * inv;
    s[3] = (float)((int)((SB      ) & 0x1FFFFF) - db) * inv;
    s[4] = (float)((int)((SB >> 21) & 0x1FFFFF) - db) * inv;
    s[5] = (float)((int)((SB >> 42) & 0x1FFFFF) - db) * inv;
    float d = rsqrtf((float)(deg + 1));
    const float* ap = atom + (size_t)node * N_IN;
    float t5[5];
#pragma unroll
    for (int k = 0; k < 5; ++k) t5[k] = d * (s[k] + d * ap[k]);  // + self loop
    float t1 = d * (s[5] + d);
    float ov[N_OUT];
#pragma unroll
    for (int o = 0; o < N_OUT; ++o) {
        float a = bias[o] * t1;
#pragma unroll
        for (int k = 0; k < 5; ++k) a = fmaf(W[o * N_IN + k], t5[k], a);
        ov[o] = fmaxf(a, 0.0f);
    }
    float4* op = (float4*)(out + (size_t)node * N_OUT);
#pragma unroll
    for (int q = 0; q < 4; ++q)
        op[q] = make_float4(ov[4 * q], ov[4 * q + 1], ov[4 * q + 2], ov[4 * q + 3]);
}

extern "C" void kernel_launch(void* const* d_in, const int* in_sizes, int n_in,
                              void* d_out, int out_size, void* d_ws, size_t ws_size,
                              hipStream_t stream) {
    const float* atom = (const float*)d_in[0];
    const int*   eidx = (const int*)d_in[1];   // [2, E] int32: row then col
    const float* W    = (const float*)d_in[2];
    const float* b    = (const float*)d_in[3];
    float* out = (float*)d_out;

    int n = in_sizes[0] / N_IN;       // 100000
    int e = in_sizes[1] / 2;          // 3200000
    const int* row = eidx;
    const int* col = eidx + e;

    // ws: cursor[NB] | eb[NB*CAP] i32 | qdatom[NB*BN] u64x2 | deg16[NB*BN] u16
    auto align256 = [](size_t v) { return (v + 255) & ~(size_t)255; };
    char* w = (char*)d_ws;
    int*            cursor = (int*)w;            w += align256(NB * 4);
    int*            eb     = (int*)w;            w += align256((size_t)NB * CAP * 4);
    ulonglong2*     qdatom = (ulonglong2*)w;     w += align256((size_t)NB * BN * 16);
    unsigned short* deg16  = (unsigned short*)w;

    int nchunk = ((e >> 2) + 2047) / 2048;    // 8192-edge chunks, 1 per block
    if (nchunk < 1) nchunk = 1;

    hipMemsetAsync(cursor, 0, NB * sizeof(int), stream);
    partition_kernel<<<nchunk, 1024, 0, stream>>>(row, col, e, eb, cursor);
    deg_quant_kernel<<<NB, 1024, 0, stream>>>(eb, cursor, atom, qdatom, deg16, n);
    accum_final<<<NB, 1024, 0, stream>>>(eb, cursor, qdatom, deg16, atom, W, b, out, n);
}

// Round 8
// 119.928 us; speedup vs baseline: 1.2369x; 1.0331x over previous
//
#include <hip/hip_runtime.h>

#define N_IN 5
#define N_OUT 16
#define NB 256           // bins; NB*BN = 102400 >= 100000 nodes
#define BN 400           // nodes per bin
#define CAP 14336        // bucket capacity (mean 12500, sigma~111 -> +16 sigma)
#define QSCALE 1024.0f
#define QBIAS 8192
#define BIN_MAGIC 10737419ull
// bin = node/400 via magic: (node * 10737419) >> 32, exact for node <= 102400.
// Packed edge: (l << 17) | row  (l < 400 -> 9 bits; row < 131072 -> 17 bits).
// meta: (bin << 14) | rank  (rank < 12500+slack < 16384).
// qdatom: two u64 of 3x21-bit biased fields (field = q + 8192, q clamp ±8191).
// Unsliced per-node field sums stay < 2^21 for deg < 128 (deg ~ Poisson(32)).

__device__ __forceinline__ int bin_of(int c) {
    return (int)(((unsigned long long)(unsigned)c * BIN_MAGIC) >> 32);
}

// ---------------------------------------------------------------------------
// Partition into 256 col-bins. Grid = EXACTLY 256 blocks, each owning one
// perfectly balanced ~12500-edge chunk -> ONE fork-join sequence per block
// (R7 data: phase count per edge is the only knob that moves this kernel;
// 391-block config wasted a 1.53-round occupancy tail). Payload+meta are
// packed into statically-indexed register arrays at rank time (2 regs/edge).
// cursor[] = pure counts (zeroed by memset). Scattered stores (R4: write-
// combining neutral).
// ---------------------------------------------------------------------------
__global__ __launch_bounds__(1024) void partition_kernel(
        const int* __restrict__ row, const int* __restrict__ col,
        int e, int* __restrict__ eb, int* __restrict__ cursor) {
    __shared__ int hist[NB];
    __shared__ int base[NB];
    const int tid = threadIdx.x;
    const int e4 = e >> 2;
    const int nper = (e4 + (int)gridDim.x - 1) / (int)gridDim.x;  // 3125
    const int b0 = (int)blockIdx.x * nper;
    int lim = e4 - b0; if (lim > nper) lim = nper; if (lim < 0) lim = 0;
    const int4* rowv = (const int4*)row;
    const int4* colv = (const int4*)col;

    if (tid < NB) hist[tid] = 0;
    __syncthreads();

    int pay[4][4];    // payload (l<<17)|row  — static indices only
    int met[4][4];    // (bin<<14)|rank      — static indices only
    bool val[4];
#pragma unroll
    for (int k = 0; k < 4; ++k) {
        val[k] = (tid + k * 1024) < lim;
        if (val[k]) {
            const int idx = b0 + tid + k * 1024;
            int4 r4 = rowv[idx];
            int4 c4 = colv[idx];
            int cc[4] = {c4.x, c4.y, c4.z, c4.w};
            int rr[4] = {r4.x, r4.y, r4.z, r4.w};
#pragma unroll
            for (int j = 0; j < 4; ++j) {
                int b = bin_of(cc[j]);
                int pr = atomicAdd(&hist[b], 1);       // in-chunk rank
                pay[k][j] = ((cc[j] - b * BN) << 17) | rr[j];
                met[k][j] = (b << 14) | pr;
            }
        }
    }
    __syncthreads();
    if (tid < NB) {
        int h = hist[tid];
        base[tid] = h ? atomicAdd(&cursor[tid], h) : 0;
    }
    __syncthreads();
#pragma unroll
    for (int k = 0; k < 4; ++k) {
        if (val[k]) {
#pragma unroll
            for (int j = 0; j < 4; ++j) {
                int b = met[k][j] >> 14;
                int p = base[b] + (met[k][j] & 16383);
                if (p < CAP)                            // capacity guard (P ~ 0)
                    eb[b * CAP + p] = pay[k][j];
            }
        }
    }
    if (blockIdx.x == 0) {   // scalar tail (e % 4)
        for (int k = (e4 << 2) + tid; k < e; k += 1024) {
            int c = col[k];
            int b = bin_of(c);
            int o = atomicAdd(&cursor[b], 1);
            if (o < CAP) eb[b * CAP + o] = ((c - b * BN) << 17) | row[k];
        }
    }
}

// ---------------------------------------------------------------------------
// Block = bin: final degree hist in one pass (1 DS atomic/edge), then
// immediately dis = rsqrt(deg+1), quantized datom + deg16. (R7 exact.)
// ---------------------------------------------------------------------------
__global__ __launch_bounds__(1024) void deg_quant_kernel(
        const int* __restrict__ eb, const int* __restrict__ cursor,
        const float* __restrict__ atom,
        ulonglong2* __restrict__ qdatom, unsigned short* __restrict__ deg16,
        int n) {
    __shared__ int hist[BN];
    int bin = blockIdx.x;
    if (threadIdx.x < BN) hist[threadIdx.x] = 0;
    __syncthreads();
    int s0 = bin * CAP;
    int cnt = min(max(cursor[bin], 0), CAP);
    const int4* ebv = (const int4*)(eb + s0);
    int cnt4 = cnt >> 2;
    for (int i = threadIdx.x; i < cnt4; i += 1024) {
        int4 v = ebv[i];
        atomicAdd(&hist[v.x >> 17], 1);
        atomicAdd(&hist[v.y >> 17], 1);
        atomicAdd(&hist[v.z >> 17], 1);
        atomicAdd(&hist[v.w >> 17], 1);
    }
    for (int i = (cnt4 << 2) + (int)threadIdx.x; i < cnt; i += 1024)
        atomicAdd(&hist[eb[s0 + i] >> 17], 1);
    __syncthreads();
    int l = threadIdx.x;
    if (l >= BN) return;
    int node = bin * BN + l;
    if (node >= n) return;
    int deg = hist[l];
    deg16[node] = (unsigned short)deg;
    float d = rsqrtf((float)(deg + 1));
    const float* ap = atom + (size_t)node * N_IN;
    unsigned long long f[6];
#pragma unroll
    for (int k = 0; k < 5; ++k) {
        int q = __float2int_rn(d * ap[k] * QSCALE);
        q = min(max(q, -8191), 8191);
        f[k] = (unsigned long long)(q + QBIAS);
    }
    f[5] = (unsigned long long)(__float2int_rn(d * QSCALE) + QBIAS);
    ulonglong2 v;
    v.x = f[0] | (f[1] << 21) | (f[2] << 42);
    v.y = f[3] | (f[4] << 21) | (f[5] << 42);
    qdatom[node] = v;
}

// ---------------------------------------------------------------------------
// Block = bin: accumulate (2 u64 DS atomics/edge, 4-way ILP) then fused
// epilogue: debias with deg16, self-loop, Linear W/b, ReLU, 64B/node store.
// (R7 exact.)
// ---------------------------------------------------------------------------
__global__ __launch_bounds__(1024) void accum_final(
        const int* __restrict__ eb, const int* __restrict__ cursor,
        const ulonglong2* __restrict__ qdatom,
        const unsigned short* __restrict__ deg16,
        const float* __restrict__ atom,
        const float* __restrict__ W, const float* __restrict__ bias,
        float* __restrict__ out, int n) {
    __shared__ unsigned long long accA[BN];   // 3.2 KB
    __shared__ unsigned long long accB[BN];   // 3.2 KB
    int bin = blockIdx.x;
    if (threadIdx.x < BN) { accA[threadIdx.x] = 0ull; accB[threadIdx.x] = 0ull; }
    __syncthreads();
    int s0 = bin * CAP;
    int cnt = min(max(cursor[bin], 0), CAP);
    const int4* ebv = (const int4*)(eb + s0);
    int cnt4 = cnt >> 2;
    for (int i = threadIdx.x; i < cnt4; i += 1024) {
        int4 v = ebv[i];
        ulonglong2 q0 = qdatom[v.x & 0x1FFFF];
        ulonglong2 q1 = qdatom[v.y & 0x1FFFF];
        ulonglong2 q2 = qdatom[v.z & 0x1FFFF];
        ulonglong2 q3 = qdatom[v.w & 0x1FFFF];
        atomicAdd(&accA[v.x >> 17], q0.x);
        atomicAdd(&accB[v.x >> 17], q0.y);
        atomicAdd(&accA[v.y >> 17], q1.x);
        atomicAdd(&accB[v.y >> 17], q1.y);
        atomicAdd(&accA[v.z >> 17], q2.x);
        atomicAdd(&accB[v.z >> 17], q2.y);
        atomicAdd(&accA[v.w >> 17], q3.x);
        atomicAdd(&accB[v.w >> 17], q3.y);
    }
    for (int i = (cnt4 << 2) + (int)threadIdx.x; i < cnt; i += 1024) {
        int v = eb[s0 + i];
        ulonglong2 q = qdatom[v & 0x1FFFF];
        atomicAdd(&accA[v >> 17], q.x);
        atomicAdd(&accB[v >> 17], q.y);
    }
    __syncthreads();
    int l = threadIdx.x;
    if (l >= BN) return;
    int node = bin * BN + l;
    if (node >= n) return;
    unsigned long long SA = accA[l], SB = accB[l];
    int deg = deg16[node];
    int db = deg * QBIAS;
    const float inv = 1.0f / QSCALE;
    float s[6];
    s[0] = (float)((int)((SA      ) & 0x1FFFFF) - db) * inv;
    s[1] = (float)((int)((SA >> 21) & 0x1FFFFF) - db) * inv;
    s[2] = (float)((int)((SA >> 42) & 0x1FFFFF) - db) * inv;
    s[3] = (float)((int)((SB      ) & 0x1FFFFF) - db) * inv;
    s[4] = (float)((int)((SB >> 21) & 0x1FFFFF) - db) * inv;
    s[5] = (float)((int)((SB >> 42) & 0x1FFFFF) - db) * inv;
    float d = rsqrtf((float)(deg + 1));
    const float* ap = atom + (size_t)node * N_IN;
    float t5[5];
#pragma unroll
    for (int k = 0; k < 5; ++k) t5[k] = d * (s[k] + d * ap[k]);  // + self loop
    float t1 = d * (s[5] + d);
    float ov[N_OUT];
#pragma unroll
    for (int o = 0; o < N_OUT; ++o) {
        float a = bias[o] * t1;
#pragma unroll
        for (int k = 0; k < 5; ++k) a = fmaf(W[o * N_IN + k], t5[k], a);
        ov[o] = fmaxf(a, 0.0f);
    }
    float4* op = (float4*)(out + (size_t)node * N_OUT);
#pragma unroll
    for (int q = 0; q < 4; ++q)
        op[q] = make_float4(ov[4 * q], ov[4 * q + 1], ov[4 * q + 2], ov[4 * q + 3]);
}

extern "C" void kernel_launch(void* const* d_in, const int* in_sizes, int n_in,
                              void* d_out, int out_size, void* d_ws, size_t ws_size,
                              hipStream_t stream) {
    const float* atom = (const float*)d_in[0];
    const int*   eidx = (const int*)d_in[1];   // [2, E] int32: row then col
    const float* W    = (const float*)d_in[2];
    const float* b    = (const float*)d_in[3];
    float* out = (float*)d_out;

    int n = in_sizes[0] / N_IN;       // 100000
    int e = in_sizes[1] / 2;          // 3200000
    const int* row = eidx;
    const int* col = eidx + e;

    // ws: cursor[NB] | eb[NB*CAP] i32 | qdatom[NB*BN] u64x2 | deg16[NB*BN] u16
    auto align256 = [](size_t v) { return (v + 255) & ~(size_t)255; };
    char* w = (char*)d_ws;
    int*            cursor = (int*)w;            w += align256(NB * 4);
    int*            eb     = (int*)w;            w += align256((size_t)NB * CAP * 4);
    ulonglong2*     qdatom = (ulonglong2*)w;     w += align256((size_t)NB * BN * 16);
    unsigned short* deg16  = (unsigned short*)w;

    hipMemsetAsync(cursor, 0, NB * sizeof(int), stream);
    partition_kernel<<<256, 1024, 0, stream>>>(row, col, e, eb, cursor);
    deg_quant_kernel<<<NB, 1024, 0, stream>>>(eb, cursor, atom, qdatom, deg16, n);
    accum_final<<<NB, 1024, 0, stream>>>(eb, cursor, qdatom, deg16, atom, W, b, out, n);
}

// Round 9
// 116.191 us; speedup vs baseline: 1.2766x; 1.0322x over previous
//
#include <hip/hip_runtime.h>

#define N_IN 5
#define N_OUT 16
#define NB 256           // bins; NB*BN = 102400 >= 100000 nodes
#define BN 400           // nodes per bin
#define NCH 256          // chunks (= partition grid); 12500 edges each
#define CELL 128         // per (chunk,bin) cell capacity: 48.8 mean + 11 sigma
#define QSCALE 1024.0f
#define QBIAS 8192
#define BIN_MAGIC 10737419ull
// bin = node/400 via magic: (node * 10737419) >> 32, exact for node <= 102400.
// Packed edge: (l << 17) | row  (l < 400 -> 9 bits; row < 131072 -> 17 bits).
// eb layout: [chunk][bin][CELL] -- STATIC cells, so partition needs no global
// cursor (rank atomic's return IS the slot) and no memset dispatch.
// qdatom: two u64 of 3x21-bit biased fields (field = q + 8192, q clamp ±8191).
// Unsliced per-node field sums stay < 2^21 for deg < 128 (deg ~ Poisson(32)).

__device__ __forceinline__ int bin_of(int c) {
    return (int)(((unsigned long long)(unsigned)c * BIN_MAGIC) >> 32);
}

// ---------------------------------------------------------------------------
// Partition: grid = NCH blocks, one balanced 12500-edge chunk each.
// zero-hist -> barrier -> {rank atomic -> IMMEDIATE scatter to static cell}
// -> barrier -> write cnts. Two barriers, zero global atomics, no cursor,
// no reserve phase, no registers held across barriers.
// ---------------------------------------------------------------------------
__global__ __launch_bounds__(1024) void partition_kernel(
        const int* __restrict__ row, const int* __restrict__ col,
        int e, int* __restrict__ eb, int* __restrict__ cnts) {
    __shared__ int hist[NB];
    const int tid = threadIdx.x;
    const int e4 = e >> 2;
    const int nper = (e4 + NCH - 1) / NCH;        // 3125
    const int b0 = (int)blockIdx.x * nper;
    int lim = e4 - b0; if (lim > nper) lim = nper; if (lim < 0) lim = 0;
    const int cbase = (int)blockIdx.x * NB;        // this chunk's cell row
    const int4* rowv = (const int4*)row;
    const int4* colv = (const int4*)col;

    if (tid < NB) hist[tid] = 0;
    __syncthreads();

#pragma unroll
    for (int k = 0; k < 4; ++k) {
        const int t = tid + k * 1024;
        if (t < lim) {
            const int idx = b0 + t;
            int4 r4 = rowv[idx];
            int4 c4 = colv[idx];
            int cc[4] = {c4.x, c4.y, c4.z, c4.w};
            int rr[4] = {r4.x, r4.y, r4.z, r4.w};
#pragma unroll
            for (int j = 0; j < 4; ++j) {
                int b = bin_of(cc[j]);
                int pr = atomicAdd(&hist[b], 1);   // rank == final slot
                if (pr < CELL)                     // overflow guard (P ~ 1e-20)
                    eb[((cbase + b) << 7) + pr] = ((cc[j] - b * BN) << 17) | rr[j];
            }
        }
    }
    if (blockIdx.x == 0) {   // scalar tail (e % 4 <= 3) into block 0's cells
        for (int k = (e4 << 2) + tid; k < e; k += 1024) {
            int c = col[k];
            int b = bin_of(c);
            int pr = atomicAdd(&hist[b], 1);
            if (pr < CELL)
                eb[((cbase + b) << 7) + pr] = ((c - b * BN) << 17) | row[k];
        }
    }
    __syncthreads();
    if (tid < NB) cnts[cbase + tid] = min(hist[tid], CELL);
}

// ---------------------------------------------------------------------------
// Block = bin: degree histogram over 256 static cells (4 threads/cell,
// int4 loads, per-element cnt mask), then dis = rsqrt(deg+1), quantized
// qdatom + deg16.
// ---------------------------------------------------------------------------
__global__ __launch_bounds__(1024) void deg_quant_kernel(
        const int* __restrict__ eb, const int* __restrict__ cnts,
        const float* __restrict__ atom,
        ulonglong2* __restrict__ qdatom, unsigned short* __restrict__ deg16,
        int n) {
    __shared__ int hist[BN];
    const int bin = blockIdx.x;
    const int tid = threadIdx.x;
    if (tid < BN) hist[tid] = 0;
    __syncthreads();
    const int c = tid >> 2, sub = tid & 3;         // 4 threads per cell
    const int cnt = cnts[c * NB + bin];
    const int4* cell = (const int4*)(eb + (((size_t)c * NB + bin) << 7));
    const int quads = (cnt + 3) >> 2;
    for (int q = sub; q < quads; q += 4) {
        int4 v = cell[q];
        int base = q << 2;
        if (base + 0 < cnt) atomicAdd(&hist[v.x >> 17], 1);
        if (base + 1 < cnt) atomicAdd(&hist[v.y >> 17], 1);
        if (base + 2 < cnt) atomicAdd(&hist[v.z >> 17], 1);
        if (base + 3 < cnt) atomicAdd(&hist[v.w >> 17], 1);
    }
    __syncthreads();
    const int l = tid;
    if (l >= BN) return;
    const int node = bin * BN + l;
    if (node >= n) return;
    int deg = hist[l];
    deg16[node] = (unsigned short)deg;
    float d = rsqrtf((float)(deg + 1));
    const float* ap = atom + (size_t)node * N_IN;
    unsigned long long f[6];
#pragma unroll
    for (int k = 0; k < 5; ++k) {
        int q = __float2int_rn(d * ap[k] * QSCALE);
        q = min(max(q, -8191), 8191);
        f[k] = (unsigned long long)(q + QBIAS);
    }
    f[5] = (unsigned long long)(__float2int_rn(d * QSCALE) + QBIAS);
    ulonglong2 v;
    v.x = f[0] | (f[1] << 21) | (f[2] << 42);
    v.y = f[3] | (f[4] << 21) | (f[5] << 42);
    qdatom[node] = v;
}

// ---------------------------------------------------------------------------
// Block = bin: accumulate over 256 static cells (2 u64 DS atomics/edge,
// per-element cnt mask) then fused epilogue: debias with deg16, self-loop,
// Linear W/b, ReLU, 64B/node store.
// ---------------------------------------------------------------------------
__global__ __launch_bounds__(1024) void accum_final(
        const int* __restrict__ eb, const int* __restrict__ cnts,
        const ulonglong2* __restrict__ qdatom,
        const unsigned short* __restrict__ deg16,
        const float* __restrict__ atom,
        const float* __restrict__ W, const float* __restrict__ bias,
        float* __restrict__ out, int n) {
    __shared__ unsigned long long accA[BN];   // 3.2 KB
    __shared__ unsigned long long accB[BN];   // 3.2 KB
    const int bin = blockIdx.x;
    const int tid = threadIdx.x;
    if (tid < BN) { accA[tid] = 0ull; accB[tid] = 0ull; }
    __syncthreads();
    const int c = tid >> 2, sub = tid & 3;         // 4 threads per cell
    const int cnt = cnts[c * NB + bin];
    const int4* cell = (const int4*)(eb + (((size_t)c * NB + bin) << 7));
    const int quads = (cnt + 3) >> 2;
    for (int q = sub; q < quads; q += 4) {
        int4 v = cell[q];
        int base = q << 2;
        if (base + 0 < cnt) {
            ulonglong2 q0 = qdatom[v.x & 0x1FFFF];
            atomicAdd(&accA[v.x >> 17], q0.x);
            atomicAdd(&accB[v.x >> 17], q0.y);
        }
        if (base + 1 < cnt) {
            ulonglong2 q1 = qdatom[v.y & 0x1FFFF];
            atomicAdd(&accA[v.y >> 17], q1.x);
            atomicAdd(&accB[v.y >> 17], q1.y);
        }
        if (base + 2 < cnt) {
            ulonglong2 q2 = qdatom[v.z & 0x1FFFF];
            atomicAdd(&accA[v.z >> 17], q2.x);
            atomicAdd(&accB[v.z >> 17], q2.y);
        }
        if (base + 3 < cnt) {
            ulonglong2 q3 = qdatom[v.w & 0x1FFFF];
            atomicAdd(&accA[v.w >> 17], q3.x);
            atomicAdd(&accB[v.w >> 17], q3.y);
        }
    }
    __syncthreads();
    const int l = tid;
    if (l >= BN) return;
    const int node = bin * BN + l;
    if (node >= n) return;
    unsigned long long SA = accA[l], SB = accB[l];
    int deg = deg16[node];
    int db = deg * QBIAS;
    const float inv = 1.0f / QSCALE;
    float s[6];
    s[0] = (float)((int)((SA      ) & 0x1FFFFF) - db) * inv;
    s[1] = (float)((int)((SA >> 21) & 0x1FFFFF) - db) * inv;
    s[2] = (float)((int)((SA >> 42) & 0x1FFFFF) - db) * inv;
    s[3] = (float)((int)((SB      ) & 0x1FFFFF) - db) * inv;
    s[4] = (float)((int)((SB >> 21) & 0x1FFFFF) - db) * inv;
    s[5] = (float)((int)((SB >> 42) & 0x1FFFFF) - db) * inv;
    float d = rsqrtf((float)(deg + 1));
    const float* ap = atom + (size_t)node * N_IN;
    float t5[5];
#pragma unroll
    for (int k = 0; k < 5; ++k) t5[k] = d * (s[k] + d * ap[k]);  // + self loop
    float t1 = d * (s[5] + d);
    float ov[N_OUT];
#pragma unroll
    for (int o = 0; o < N_OUT; ++o) {
        float a = bias[o] * t1;
#pragma unroll
        for (int k = 0; k < 5; ++k) a = fmaf(W[o * N_IN + k], t5[k], a);
        ov[o] = fmaxf(a, 0.0f);
    }
    float4* op = (float4*)(out + (size_t)node * N_OUT);
#pragma unroll
    for (int q = 0; q < 4; ++q)
        op[q] = make_float4(ov[4 * q], ov[4 * q + 1], ov[4 * q + 2], ov[4 * q + 3]);
}

extern "C" void kernel_launch(void* const* d_in, const int* in_sizes, int n_in,
                              void* d_out, int out_size, void* d_ws, size_t ws_size,
                              hipStream_t stream) {
    const float* atom = (const float*)d_in[0];
    const int*   eidx = (const int*)d_in[1];   // [2, E] int32: row then col
    const float* W    = (const float*)d_in[2];
    const float* b    = (const float*)d_in[3];
    float* out = (float*)d_out;

    int n = in_sizes[0] / N_IN;       // 100000
    int e = in_sizes[1] / 2;          // 3200000
    const int* row = eidx;
    const int* col = eidx + e;

    // ws: eb[NCH*NB*CELL] i32 (33.5 MB) | cnts[NCH*NB] i32 (256 KB) |
    //     qdatom[NB*BN] u64x2 (1.6 MB) | deg16[NB*BN] u16 (0.2 MB)
    // No memset needed: cnts is fully written by partition every call.
    auto align256 = [](size_t v) { return (v + 255) & ~(size_t)255; };
    char* w = (char*)d_ws;
    int*            eb     = (int*)w;         w += align256((size_t)NCH * NB * CELL * 4);
    int*            cnts   = (int*)w;         w += align256((size_t)NCH * NB * 4);
    ulonglong2*     qdatom = (ulonglong2*)w;  w += align256((size_t)NB * BN * 16);
    unsigned short* deg16  = (unsigned short*)w;

    partition_kernel<<<NCH, 1024, 0, stream>>>(row, col, e, eb, cnts);
    deg_quant_kernel<<<NB, 1024, 0, stream>>>(eb, cnts, atom, qdatom, deg16, n);
    accum_final<<<NB, 1024, 0, stream>>>(eb, cnts, qdatom, deg16, atom, W, b, out, n);
}